// Round 10
// baseline (189.397 us; speedup 1.0000x reference)
//
#include <hip/hip_runtime.h>

#define N_NODES 100000
#define N_EDGES 1000000
#define D 64
#define N_TYPES 16

#define NPB 64                                   // nodes per bucket (dst >> 6)
#define NBUCK ((N_NODES + NPB - 1) / NPB)        // 1563
#define NBLK 256                                 // edge chunks in sort
#define CHUNK ((N_EDGES + NBLK - 1) / NBLK)      // 3907
#define ECAP 1024                                // per-bucket edge cap (mean 640, sd ~25)

// ---------------- workspace layout (4-byte units) ----------------
#define WS_TBL    0
#define WS_BTOT   (WS_TBL + NBUCK * NBLK)
#define WS_BSTART (WS_BTOT + NBUCK)
#define WS_EBUF   (WS_BSTART + NBUCK + 1)
#define WS_TOTAL  (WS_EBUF + N_EDGES + 64)

// ---- K0: per-chunk edge-bucket histogram (LDS only, plain stores) ----
__global__ void __launch_bounds__(256)
hist_edges(const int* __restrict__ dst, int* __restrict__ tbl) {
    __shared__ int hb[NBUCK];
    int b = blockIdx.x, tid = threadIdx.x;
    for (int i = tid; i < NBUCK; i += 256) hb[i] = 0;
    __syncthreads();
    int beg = b * CHUNK, end = min(beg + CHUNK, N_EDGES);
    for (int e = beg + tid; e < end; e += 256)
        atomicAdd(&hb[dst[e] >> 6], 1);
    __syncthreads();
    for (int i = tid; i < NBUCK; i += 256) tbl[i * NBLK + b] = hb[i];
}

// ---- K1: wave-per-bucket exclusive scan of the 256 chunk counts ----
__global__ void __launch_bounds__(512)
scan_cols(int* __restrict__ tbl, int* __restrict__ btot) {
    int wave = blockIdx.x * 8 + (threadIdx.x >> 6);
    int lane = threadIdx.x & 63;
    if (wave >= NBUCK) return;
    int4 v = ((int4*)(tbl + wave * NBLK))[lane];
    int s01 = v.x + v.y;
    int s = s01 + v.z + v.w;
    int incl = s;
    for (int o = 1; o < 64; o <<= 1) {
        int u = __shfl_up(incl, o, 64);
        if (lane >= o) incl += u;
    }
    int excl = incl - s;
    int4 w;
    w.x = excl; w.y = excl + v.x; w.z = excl + s01; w.w = excl + s01 + v.z;
    ((int4*)(tbl + wave * NBLK))[lane] = w;
    if (lane == 63) btot[wave] = incl;
}

// ---- K2: single-block scan of 1563 bucket totals -> bucket starts ----
__global__ void __launch_bounds__(1024)
scan_buckets(const int* __restrict__ btot, int* __restrict__ bstart) {
    __shared__ int sh[1024];
    int t = threadIdx.x;
    int i0 = 2 * t, i1 = 2 * t + 1;
    int v0 = (i0 < NBUCK) ? btot[i0] : 0;
    int v1 = (i1 < NBUCK) ? btot[i1] : 0;
    int s = v0 + v1;
    sh[t] = s;
    __syncthreads();
    for (int o = 1; o < 1024; o <<= 1) {
        int u = (t >= o) ? sh[t - o] : 0;
        __syncthreads();
        sh[t] += u;
        __syncthreads();
    }
    int excl = sh[t] - s;
    if (i0 <= NBUCK) bstart[i0] = excl;
    if (i1 <= NBUCK) bstart[i1] = excl + v0;
}

// ---- K3: LDS-staged place: local counting sort, then burst copy-out ----
__global__ void __launch_bounds__(512)
place_staged(const int* __restrict__ src, const int* __restrict__ dst,
             const int* __restrict__ tbl, const int* __restrict__ bstart,
             unsigned* __restrict__ ebuf) {
    __shared__ int hb[NBUCK];                    // counts -> cursors
    __shared__ int gb[NBUCK];                    // global base - local offset
    __shared__ uint2 stage[CHUNK];
    __shared__ int wpart[8];

    int b = blockIdx.x, tid = threadIdx.x;
    int lane = tid & 63, wv = tid >> 6;
    for (int i = tid; i < NBUCK; i += 512) hb[i] = 0;
    __syncthreads();
    int beg = b * CHUNK, end = min(beg + CHUNK, N_EDGES);
    for (int e = beg + tid; e < end; e += 512)
        atomicAdd(&hb[dst[e] >> 6], 1);
    __syncthreads();

    // block-exclusive scan over 1563 counters, 4 per thread
    int a[4], s = 0;
#pragma unroll
    for (int j = 0; j < 4; ++j) {
        int idx = tid * 4 + j;
        a[j] = (idx < NBUCK) ? hb[idx] : 0;
        s += a[j];
    }
    int incl = s;
    for (int o = 1; o < 64; o <<= 1) {
        int u = __shfl_up(incl, o, 64);
        if (lane >= o) incl += u;
    }
    if (lane == 63) wpart[wv] = incl;
    __syncthreads();
    if (tid == 0) {
        int r = 0;
        for (int w = 0; w < 8; ++w) { int tmp = wpart[w]; wpart[w] = r; r += tmp; }
    }
    __syncthreads();
    int run = incl - s + wpart[wv];
#pragma unroll
    for (int j = 0; j < 4; ++j) {
        int idx = tid * 4 + j;
        if (idx < NBUCK) {
            gb[idx] = bstart[idx] + tbl[idx * NBLK + b] - run;
            hb[idx] = run;                       // cursor = local exclusive offset
            run += a[j];
        }
    }
    __syncthreads();
    // stage edges sorted by bucket (LDS atomics only)
    for (int e = beg + tid; e < end; e += 512) {
        int d = dst[e];
        int pos = atomicAdd(&hb[d >> 6], 1);
        uint2 v; v.x = (unsigned)d; v.y = (unsigned)src[e];
        stage[pos] = v;
    }
    __syncthreads();
    // burst copy-out: idx-consecutive -> ebuf-consecutive within bucket runs
    int cnt = end - beg;
    for (int idx = tid; idx < cnt; idx += 512) {
        uint2 v = stage[idx];
        int bk = (int)(v.x >> 6);
        ebuf[gb[bk] + idx] = ((v.x & (NPB - 1)) << 20) | v.y;
    }
}

// ---- K4: fused per-bucket gather+mean+type-routed linear (64-node tile) ----
__global__ void __launch_bounds__(512)
bucket_conv(const float* __restrict__ feat,
            const float* __restrict__ gate_W, const float* __restrict__ gate_b,
            const int* __restrict__ ntype2,
            const int* __restrict__ bstart, const unsigned* __restrict__ ebuf,
            float* __restrict__ out) {
    __shared__ int hist[NPB];
    __shared__ int offL[NPB];
    __shared__ int curL[NPB];
    __shared__ int sortedL[ECAP];                // 4 KB
    __shared__ float rowfull[NPB * D];           // 16 KB: per-node means
    __shared__ unsigned char ord[NPB];
    __shared__ unsigned char typ[NPB];
    __shared__ int tc[N_TYPES], tcur[N_TYPES];

    int k = blockIdx.x, tid = threadIdx.x;
    int lane = tid & 63, wv = tid >> 6;
    if (tid < NPB) hist[tid] = 0;
    __syncthreads();
    int beg = bstart[k];
    int ecnt = bstart[k + 1] - beg;
    if (ecnt > ECAP) ecnt = ECAP;                // not hit for this graph (max ~760)
    for (int i = tid; i < ecnt; i += 512)
        atomicAdd(&hist[ebuf[beg + i] >> 20], 1);
    __syncthreads();
    if (tid < NPB) {                             // wave-0 shfl scan over 64 counters
        int v = hist[tid];
        int incl = v;
        for (int o = 1; o < 64; o <<= 1) {
            int u = __shfl_up(incl, o, 64);
            if (lane >= o) incl += u;
        }
        offL[tid] = incl - v;
        curL[tid] = incl - v;
    }
    __syncthreads();
    for (int i = tid; i < ecnt; i += 512) {
        unsigned p = ebuf[beg + i];
        int pos = atomicAdd(&curL[p >> 20], 1);
        sortedL[pos] = (int)(p & 0xFFFFFu);
    }
    __syncthreads();

    // per-node mean in registers: half-wave (32 lanes) per node, h = dim pair
    int sub = lane >> 5, h = lane & 31;
    const float2* __restrict__ F = (const float2*)feat;
    int node0 = k * NPB;
#pragma unroll
    for (int it = 0; it < 4; ++it) {
        int n = (wv * 4 + it) * 2 + sub;         // 0..63
        int cnt = hist[n], o = offL[n];
        float sx = 0.0f, sy = 0.0f;
        int j = 0;
        for (; j + 4 <= cnt; j += 4) {
            int s0 = sortedL[o + j + 0];
            int s1 = sortedL[o + j + 1];
            int s2 = sortedL[o + j + 2];
            int s3 = sortedL[o + j + 3];
            float2 v0 = F[s0 * 32 + h];
            float2 v1 = F[s1 * 32 + h];
            float2 v2 = F[s2 * 32 + h];
            float2 v3 = F[s3 * 32 + h];
            sx += (v0.x + v1.x) + (v2.x + v3.x);
            sy += (v0.y + v1.y) + (v2.y + v3.y);
        }
        for (; j < cnt; ++j) {
            int s = sortedL[o + j];
            float2 v = F[s * 32 + h];
            sx += v.x; sy += v.y;
        }
        float scale = (cnt > 1) ? (1.0f / (float)cnt) : 1.0f;
        float2 r; r.x = sx * scale; r.y = sy * scale;
        ((float2*)rowfull)[n * 32 + h] = r;
    }

    // type-sort the bucket's nodes
    int nvalid = N_NODES - node0; if (nvalid > NPB) nvalid = NPB;
    if (tid < N_TYPES) tc[tid] = 0;
    __syncthreads();
    int myt = -1;
    if (tid < nvalid) { myt = ntype2[node0 + tid]; atomicAdd(&tc[myt], 1); }
    __syncthreads();
    if (tid == 0) {
        int r = 0;
        for (int t = 0; t < N_TYPES; ++t) { tcur[t] = r; r += tc[t]; }
    }
    __syncthreads();
    if (tid < nvalid) {
        int p = atomicAdd(&tcur[myt], 1);
        ord[p] = (unsigned char)tid;
        typ[p] = (unsigned char)myt;
    }
    __syncthreads();

    // apply: wave wv owns sorted chunk [wv*8, wv*8+8); W column in VGPRs,
    // reloaded only on type change (type-sorted -> ~2 loads/chunk)
    int i0 = wv * 8, i1 = i0 + 8; if (i1 > nvalid) i1 = nvalid;
    int tprev = -1;
    float wreg[D];
    float bias = 0.0f;
    for (int i = i0; i < i1; ++i) {
        int n = (int)ord[i];
        int t = (int)typ[i];
        if (t != tprev) {
            tprev = t;
            const float* __restrict__ W = gate_W + t * D * D;
#pragma unroll
            for (int d = 0; d < D; ++d) wreg[d] = W[d * D + lane];
            bias = gate_b[t * D + lane];
        }
        const float* __restrict__ ar = &rowfull[n * D];
        float a0 = bias, a1 = 0.0f, a2 = 0.0f, a3 = 0.0f;
#pragma unroll
        for (int d = 0; d < D; d += 4) {
            float4 av = *(const float4*)(ar + d);            // LDS b128 broadcast
            a0 = fmaf(av.x, wreg[d + 0], a0);
            a1 = fmaf(av.y, wreg[d + 1], a1);
            a2 = fmaf(av.z, wreg[d + 2], a2);
            a3 = fmaf(av.w, wreg[d + 3], a3);
        }
        out[(node0 + n) * D + lane] = (a0 + a1) + (a2 + a3);
    }
}

// ================= fallback (round-1 fp32 atomic path) =================
__global__ void scatter_feat(const float* __restrict__ feat, const int* __restrict__ src,
                             const int* __restrict__ dst, float* __restrict__ accum) {
    long long idx = (long long)blockIdx.x * blockDim.x + threadIdx.x;
    if (idx >= (long long)N_EDGES * D) return;
    int e = (int)(idx >> 6), d = (int)(idx & 63);
    atomicAdd(accum + dst[e] * D + d, feat[src[e] * D + d]);
}
__global__ void scatter_deg(const int* __restrict__ dst, float* __restrict__ deg) {
    int e = blockIdx.x * blockDim.x + threadIdx.x;
    if (e >= N_EDGES) return;
    atomicAdd(deg + dst[e], 1.0f);
}
__global__ void apply_linear(const float* __restrict__ gate_W, const float* __restrict__ gate_b,
                             const int* __restrict__ ntype2, const float* __restrict__ deg,
                             float* __restrict__ out) {
    int node = blockIdx.x * (blockDim.x >> 6) + (threadIdx.x >> 6);
    int lane = threadIdx.x & 63;
    if (node >= N_NODES) return;
    int t = ntype2[node];
    float dv = deg[node]; dv = dv > 1.0f ? dv : 1.0f;
    float nv = out[node * D + lane] / dv;
    const float* W = gate_W + t * D * D;
    float acc = gate_b[t * D + lane];
#pragma unroll 16
    for (int d = 0; d < D; ++d)
        acc = fmaf(__shfl(nv, d, 64), W[d * D + lane], acc);
    out[node * D + lane] = acc;
}
// =======================================================================

extern "C" void kernel_launch(void* const* d_in, const int* in_sizes, int n_in,
                              void* d_out, int out_size, void* d_ws, size_t ws_size,
                              hipStream_t stream) {
    const float* feat   = (const float*)d_in[0];
    const float* gate_W = (const float*)d_in[1];
    const float* gate_b = (const float*)d_in[2];
    const int*   src    = (const int*)d_in[3];
    const int*   dst    = (const int*)d_in[4];
    const int*   ntype2 = (const int*)d_in[5];
    float* out = (float*)d_out;

    if (ws_size >= (size_t)WS_TOTAL * 4) {
        int* ws = (int*)d_ws;
        int* tbl       = ws + WS_TBL;
        int* btot      = ws + WS_BTOT;
        int* bstart    = ws + WS_BSTART;
        unsigned* ebuf = (unsigned*)(ws + WS_EBUF);

        hist_edges<<<NBLK, 256, 0, stream>>>(dst, tbl);
        scan_cols<<<(NBUCK + 7) / 8, 512, 0, stream>>>(tbl, btot);
        scan_buckets<<<1, 1024, 0, stream>>>(btot, bstart);
        place_staged<<<NBLK, 512, 0, stream>>>(src, dst, tbl, bstart, ebuf);
        bucket_conv<<<NBUCK, 512, 0, stream>>>(feat, gate_W, gate_b, ntype2,
                                               bstart, ebuf, out);
    } else {
        // fallback: round-1 fp32 atomic path (known-good, ~434 us)
        float* deg = (float*)d_ws;
        hipMemsetAsync(out, 0, sizeof(float) * N_NODES * D, stream);
        hipMemsetAsync(deg, 0, sizeof(float) * N_NODES, stream);
        long long total = (long long)N_EDGES * D;
        scatter_feat<<<(int)((total + 255) / 256), 256, 0, stream>>>(feat, src, dst, out);
        scatter_deg<<<(N_EDGES + 255) / 256, 256, 0, stream>>>(dst, deg);
        apply_linear<<<(N_NODES + 3) / 4, 256, 0, stream>>>(gate_W, gate_b, ntype2, deg, out);
    }
}